// Round 3
// baseline (205.265 us; speedup 1.0000x reference)
//
#include <hip/hip_runtime.h>

// B=32, T=2048, D=1024 (fp32)
// out[b,d] = sum_t softmax_t(tanh(x[b,t,:]·W + bias[t])) * x[b,t,d]
// tanh in (-1,1) -> softmax needs no max subtraction -> single pass.
// Register-double-buffered streaming + last-block-per-batch combine.

#define PSTR 1032  // floats per partial: [0]=lsum, [8..1032)=acc[1024]

__global__ __launch_bounds__(256) void fused_all(
    const float* __restrict__ x, const float* __restrict__ w,
    const float* __restrict__ bias, float* __restrict__ partials,
    unsigned int* __restrict__ counters, float* __restrict__ out,
    int T, int C)
{
    const int c = blockIdx.x;      // T-chunk
    const int b = blockIdx.y;      // batch
    const int wv = threadIdx.x >> 6;
    const int lane = threadIdx.x & 63;
    const int tid = threadIdx.x;

    const int rows = T / C;        // rows per chunk, multiple of 8 (host enforces)
    const int r0 = c * rows;

    const float4* w4 = (const float4*)w;
    float4 wf[4];
#pragma unroll
    for (int k = 0; k < 4; ++k) wf[k] = w4[lane + k * 64];

    const float4* xb = (const float4*)x + (size_t)b * T * 256;

    float4 acc[4] = {{0,0,0,0},{0,0,0,0},{0,0,0,0},{0,0,0,0}};
    float lsum = 0.f;

    float4 ca[2][4], na[2][4];

    auto loadpair = [&](float4 (&dst)[2][4], int rbase) {
#pragma unroll
        for (int j = 0; j < 2; ++j) {
            const float4* xr = xb + (size_t)(rbase + j) * 256;
#pragma unroll
            for (int k = 0; k < 4; ++k) dst[j][k] = xr[lane + k * 64];
        }
    };
    auto compute = [&](float4 (&a)[2][4], int rbase) {
#pragma unroll
        for (int j = 0; j < 2; ++j) {
            float d = 0.f;
#pragma unroll
            for (int k = 0; k < 4; ++k)
                d += a[j][k].x * wf[k].x + a[j][k].y * wf[k].y
                   + a[j][k].z * wf[k].z + a[j][k].w * wf[k].w;
#pragma unroll
            for (int off = 1; off < 64; off <<= 1)
                d += __shfl_xor(d, off);
            float e = __expf(tanhf(d + bias[rbase + j]));
            lsum += e;
#pragma unroll
            for (int k = 0; k < 4; ++k) {
                acc[k].x += e * a[j][k].x; acc[k].y += e * a[j][k].y;
                acc[k].z += e * a[j][k].z; acc[k].w += e * a[j][k].w;
            }
        }
    };

    int base = r0 + wv * 2;
    const int lastbase = r0 + rows - 8 + wv * 2;
    loadpair(ca, base);
    for (; base < lastbase; base += 8) {
        loadpair(na, base + 8);     // prefetch next pair (stays in flight)
        compute(ca, base);
#pragma unroll
        for (int j = 0; j < 2; ++j)
#pragma unroll
            for (int k = 0; k < 4; ++k) ca[j][k] = na[j][k];
    }
    compute(ca, base);              // final pair

    // combine 4 waves via LDS
    __shared__ float lacc[4 * 1024];
    __shared__ float lls[4];
    __shared__ unsigned int ticket_s;
    float4* lacc4 = (float4*)lacc;
#pragma unroll
    for (int k = 0; k < 4; ++k) lacc4[wv * 256 + k * 64 + lane] = acc[k];
    if (lane == 0) lls[wv] = lsum;
    __syncthreads();

    float4 o0 = lacc4[tid];
    float4 o1 = lacc4[256 + tid];
    float4 o2 = lacc4[512 + tid];
    float4 o3 = lacc4[768 + tid];
    float4 o;
    o.x = (o0.x + o1.x) + (o2.x + o3.x);
    o.y = (o0.y + o1.y) + (o2.y + o3.y);
    o.z = (o0.z + o1.z) + (o2.z + o3.z);
    o.w = (o0.w + o1.w) + (o2.w + o3.w);

    float* p = partials + (size_t)(b * C + c) * PSTR;
    if (tid == 0) p[0] = (lls[0] + lls[1]) + (lls[2] + lls[3]);
    ((float4*)(p + 8))[tid] = o;

    // last block of this batch combines
    __threadfence();               // release: my partial visible device-wide
    __syncthreads();
    if (tid == 0) ticket_s = atomicAdd(&counters[b], 1u);
    __syncthreads();
    if (ticket_s == (unsigned)(C - 1)) {
        __threadfence();           // acquire: others' partials visible
        float L = 0.f;
        float4 s = {0.f, 0.f, 0.f, 0.f};
        for (int cc = 0; cc < C; ++cc) {
            const float* q = partials + (size_t)(b * C + cc) * PSTR;
            L += q[0];
            float4 a = ((const float4*)(q + 8))[tid];
            s.x += a.x; s.y += a.y; s.z += a.z; s.w += a.w;
        }
        float inv = 1.f / L;
        float4 r; r.x = s.x * inv; r.y = s.y * inv; r.z = s.z * inv; r.w = s.w * inv;
        ((float4*)out)[b * 256 + tid] = r;
    }
}

extern "C" void kernel_launch(void* const* d_in, const int* in_sizes, int n_in,
                              void* d_out, int out_size, void* d_ws, size_t ws_size,
                              hipStream_t stream) {
    const float* x    = (const float*)d_in[0];   // [B,T,D]
    const float* w    = (const float*)d_in[1];   // [D,1]
    const float* bias = (const float*)d_in[2];   // [T,1]
    float* out = (float*)d_out;

    int D = in_sizes[1];            // 1024
    int T = in_sizes[2];            // 2048
    int nrows = in_sizes[0] / D;    // B*T
    int B = nrows / T;              // 32

    int C = 32;
    while (C > 1 && (size_t)B * C * PSTR * sizeof(float) + B * sizeof(unsigned int) > ws_size) C >>= 1;
    while (C > 1 && (T % (C * 8)) != 0) C >>= 1;

    float* partials = (float*)d_ws;
    unsigned int* counters = (unsigned int*)((char*)d_ws + (size_t)B * C * PSTR * sizeof(float));

    hipMemsetAsync(counters, 0, B * sizeof(unsigned int), stream);
    fused_all<<<dim3(C, B), 256, 0, stream>>>(x, w, bias, partials, counters, out, T, C);
}